// Round 5
// baseline (809.958 us; speedup 1.0000x reference)
//
#include <hip/hip_runtime.h>

// HGRN BitMLP (all I/O float32):
//   x[8192,2048] -> bitlinear(w_gate[16384,2048]) -> silu(gate)*v
//   -> bitlinear(w_down[2048,8192]) -> out[8192,2048]
// Int8 activations x ternary weights -> mfma_i32_16x16x64_i8.
// v6: register-pipelined tile loop. BM=256, BK=64, 512 threads / 8 waves
// (2Mx4N), wave tile 128x64. 3x32KB LDS buffers, depth-2 glds prefetch with
// counted vmcnt(4). ONE barrier per K-tile (the publish barrier); all 12
// operand ds_read_b128 for tile it+1 are issued right after that barrier,
// a full MFMA cluster (~650cy) before first use -> every lgkm wait is free.
// Two 16-MFMA clusters per tile under setprio. Fragment-order slabs
// (zero bank conflicts).

using char8  = __attribute__((ext_vector_type(8))) signed char;
using int4v  = __attribute__((ext_vector_type(4))) int;
using half8  = __attribute__((ext_vector_type(8))) _Float16;

// async global->LDS, 16B per lane; LDS dest = wave-uniform base + lane*16
__device__ __forceinline__ void glds16(const void* g, void* l) {
  __builtin_amdgcn_global_load_lds((const __attribute__((address_space(1))) void*)g,
                                   (__attribute__((address_space(3))) void*)l, 16, 0, 0);
}

#define SB0() __builtin_amdgcn_sched_barrier(0)

// ---------------- deterministic sum(|w|) reduction (f32 input) --------------
__global__ __launch_bounds__(256) void reduce_abs_kernel(
    const float4* __restrict__ w, float* __restrict__ partials, int n4) {
  int t = threadIdx.x;
  int gid = blockIdx.x * 256 + t;
  int stride = gridDim.x * 256;
  float s = 0.f;
  for (int i = gid; i < n4; i += stride) {
    float4 u = w[i];
    s += fabsf(u.x) + fabsf(u.y) + fabsf(u.z) + fabsf(u.w);
  }
  __shared__ float sm[256];
  sm[t] = s; __syncthreads();
  for (int off = 128; off > 0; off >>= 1) {
    if (t < off) sm[t] += sm[t + off];
    __syncthreads();
  }
  if (t == 0) partials[blockIdx.x] = sm[0];
}

__global__ __launch_bounds__(256) void finalize_kernel(
    const float* __restrict__ pf, float* __restrict__ scales) {
  __shared__ float sm[256];
  int t = threadIdx.x;
  float s = pf[t] + pf[t + 256] + pf[t + 512] + pf[t + 768];
  sm[t] = s; __syncthreads();
  for (int off = 128; off > 0; off >>= 1) {
    if (t < off) sm[t] += sm[t + off];
    __syncthreads();
  }
  if (t == 0) {  // w_gate: 16384*2048 elements
    float c = fmaxf(sm[0] / 33554432.0f, 1e-5f);
    scales[0] = c; scales[2] = 1.0f / c;
  }
  __syncthreads();
  s = pf[1024 + t] + pf[1280 + t] + pf[1536 + t] + pf[1792 + t];
  sm[t] = s; __syncthreads();
  for (int off = 128; off > 0; off >>= 1) {
    if (t < off) sm[t] += sm[t + off];
    __syncthreads();
  }
  if (t == 0) {  // w_down: 2048*8192 elements
    float c = fmaxf(sm[0] / 16777216.0f, 1e-5f);
    scales[1] = c; scales[3] = 1.0f / c;
  }
}

// ------- ternary weight quant: f32 in -> {-1,0,1} int8 --------
__global__ __launch_bounds__(256) void quant_weight_kernel(
    const float4* __restrict__ w, char8* __restrict__ wq,
    const float* __restrict__ invp, int n8) {
  float inv = *invp;  // 1/clip(mean|w|,1e-5)
  int stride = gridDim.x * 256;
  for (int i = blockIdx.x * 256 + threadIdx.x; i < n8; i += stride) {
    float4 a = w[2 * i], b = w[2 * i + 1];
    float v[8] = {a.x, a.y, a.z, a.w, b.x, b.y, b.z, b.w};
    char8 o;
#pragma unroll
    for (int j = 0; j < 8; ++j) {
      float q = rintf(v[j] * inv);
      q = fminf(fmaxf(q, -1.f), 1.f);
      o[j] = (signed char)(int)q;
    }
    wq[i] = o;
  }
}

// ------- per-token RMSNorm + absmax int8 quant, f32 input (row = 2048) -------
__global__ __launch_bounds__(256) void act_quant_f32_kernel(
    const float* __restrict__ in, signed char* __restrict__ out,
    float* __restrict__ fscale) {
  const int token = blockIdx.x, t = threadIdx.x;
  const float4* row = (const float4*)(in + (size_t)token * 2048);
  float4 a = row[2 * t], b = row[2 * t + 1];
  float v[8] = {a.x, a.y, a.z, a.w, b.x, b.y, b.z, b.w};
  float ss = 0.f, am = 0.f;
#pragma unroll
  for (int j = 0; j < 8; ++j) { ss += v[j] * v[j]; am = fmaxf(am, fabsf(v[j])); }
  __shared__ float s1[256], s2[256];
  s1[t] = ss; s2[t] = am; __syncthreads();
  for (int off = 128; off > 0; off >>= 1) {
    if (t < off) { s1[t] += s1[t + off]; s2[t] = fmaxf(s2[t], s2[t + off]); }
    __syncthreads();
  }
  float r = 1.0f / sqrtf(s1[0] * (1.0f / 2048.0f) + 1e-8f);  // rsqrt(mean+RMS_EPS)
  float f = fmaxf(s2[0] * r, 1e-5f);                          // clip(max|xn|,Q_EPS)
  float s = 127.0f / f;
  if (t == 0) fscale[token] = f * (1.0f / 127.0f);            // dequant factor
  char8 o;
#pragma unroll
  for (int j = 0; j < 8; ++j) {
    float q = rintf((v[j] * r) * s);
    q = fminf(fmaxf(q, -128.f), 127.f);
    o[j] = (signed char)(int)q;
  }
  ((char8*)(out + (size_t)token * 2048))[t] = o;
}

// ------- per-token RMSNorm + absmax int8 quant, fp16 input (row = 8192) -----
__global__ __launch_bounds__(256) void act_quant_h_kernel(
    const _Float16* __restrict__ in, signed char* __restrict__ out,
    float* __restrict__ fscale) {
  const int token = blockIdx.x, t = threadIdx.x;
  const half8* row = (const half8*)(in + (size_t)token * 8192);
  float v[32];
  float ss = 0.f, am = 0.f;
#pragma unroll
  for (int c = 0; c < 4; ++c) {
    half8 u = row[c * 256 + t];
#pragma unroll
    for (int j = 0; j < 8; ++j) {
      float f = (float)u[j]; v[c * 8 + j] = f;
      ss += f * f; am = fmaxf(am, fabsf(f));
    }
  }
  __shared__ float s1[256], s2[256];
  s1[t] = ss; s2[t] = am; __syncthreads();
  for (int off = 128; off > 0; off >>= 1) {
    if (t < off) { s1[t] += s1[t + off]; s2[t] = fmaxf(s2[t], s2[t + off]); }
    __syncthreads();
  }
  float r = 1.0f / sqrtf(s1[0] * (1.0f / 8192.0f) + 1e-8f);
  float f = fmaxf(s2[0] * r, 1e-5f);
  float s = 127.0f / f;
  if (t == 0) fscale[token] = f * (1.0f / 127.0f);
#pragma unroll
  for (int c = 0; c < 4; ++c) {
    char8 o;
#pragma unroll
    for (int j = 0; j < 8; ++j) {
      float q = rintf((v[c * 8 + j] * r) * s);
      q = fminf(fmaxf(q, -128.f), 127.f);
      o[j] = (signed char)(int)q;
    }
    ((char8*)(out + (size_t)token * 8192))[c * 256 + t] = o;
  }
}

#define RD1(off) (*(const int4v*)&Ls[(off)])

// ---------------- GEMM1: z = silu(Xq@WgT[:I]) * (Xq@WgT[I:]) ----------------
// block: 256 tokens x 128 z-cols (B rows: 128 gate + 128 value).
// 8 waves 2Mx4N: wave = 128 rows x 32 z-cols (gate + value accs).
// LDS buffer (32KB): A slabs 0..15, B gate 0..7, value 8..15; slab = 1024B,
// slot l = row s*16+(l&15), bytes (l>>4)*16..+15 -> frag read = base + l*16.
__global__ __launch_bounds__(512, 2) void gemm1_kernel(
    const signed char* __restrict__ A,  // xq [8192,2048] i8
    const signed char* __restrict__ B,  // wgq [16384,2048] i8 ternary
    const float* __restrict__ f1, const float* __restrict__ cgp,
    _Float16* __restrict__ Z) {         // z fp16 [8192,8192]
  constexpr int K = 2048, I = 8192, NT = K / 64;
  constexpr int ASZ = 16384, BUF = 32768;
  __shared__ __align__(16) signed char Ls[3 * BUF];
  const int t0 = blockIdx.y * 256, n0 = blockIdx.x * 128;
  const int tid = threadIdx.x, w = tid >> 6, l = tid & 63;
  const int wr = w >> 2, wc = w & 3;
  const int lrow = l & 15, lchunk = (l >> 4) * 16;

  int4v ag[8][2], av[8][2];
#pragma unroll
  for (int i = 0; i < 8; ++i)
#pragma unroll
    for (int j = 0; j < 2; ++j) { ag[i][j] = {0,0,0,0}; av[i][j] = {0,0,0,0}; }

  // staging: 32 slabs/K-tile; wave w owns A slabs {w, w+8}, gate w, value w
  const signed char* src[4];
  int dst[4];
  src[0] = A + (size_t)(t0 + w * 16 + lrow) * K + lchunk;       dst[0] = w * 1024;
  src[1] = A + (size_t)(t0 + (w + 8) * 16 + lrow) * K + lchunk; dst[1] = (w + 8) * 1024;
  src[2] = B + (size_t)(n0 + w * 16 + lrow) * K + lchunk;       dst[2] = ASZ + w * 1024;
  src[3] = B + (size_t)(I + n0 + w * 16 + lrow) * K + lchunk;   dst[3] = ASZ + (8 + w) * 1024;

  // prologue: stage tiles 0 and 1 (8 loads/wave in flight)
#pragma unroll
  for (int p = 0; p < 2; ++p)
#pragma unroll
    for (int r = 0; r < 4; ++r) glds16(src[r] + p * 64, &Ls[p * BUF + dst[r]]);
  asm volatile("s_waitcnt vmcnt(4)" ::: "memory");  // tile 0 landed
  __builtin_amdgcn_s_barrier();
  SB0();

  const int abase = (8 * wr) * 1024 + l * 16;           // af[i] = +i*1024
  const int gbase = ASZ + (2 * wc) * 1024 + l * 16;     // bg[j] = +j*1024
  const int vbase = ASZ + (8 + 2 * wc) * 1024 + l * 16; // bv[j] = +j*1024

  // read tile-0 fragments
  int4v a0 = RD1(abase), a1 = RD1(abase + 1024), a2 = RD1(abase + 2048),
        a3 = RD1(abase + 3072), a4 = RD1(abase + 4096), a5 = RD1(abase + 5120),
        a6 = RD1(abase + 6144), a7 = RD1(abase + 7168);
  int4v bg0 = RD1(gbase), bg1 = RD1(gbase + 1024);
  int4v bv0 = RD1(vbase), bv1 = RD1(vbase + 1024);

  int curo = 0;
  for (int it = 0; it < NT; ++it) {
    int nxto = curo + BUF; if (nxto == 3 * BUF) nxto = 0;
    int stgo = nxto + BUF; if (stgo == 3 * BUF) stgo = 0;
    const bool stg = (it <= NT - 3);
    const int ko = (it + 2) * 64;

    // ---- phase A: stage 2 slabs, 16 MFMA on a0..a3 ----
    if (stg) { glds16(src[0] + ko, &Ls[stgo + dst[0]]);
               glds16(src[1] + ko, &Ls[stgo + dst[1]]); }
    __builtin_amdgcn_s_setprio(1);
    ag[0][0] = __builtin_amdgcn_mfma_i32_16x16x64_i8(a0, bg0, ag[0][0], 0, 0, 0);
    ag[0][1] = __builtin_amdgcn_mfma_i32_16x16x64_i8(a0, bg1, ag[0][1], 0, 0, 0);
    av[0][0] = __builtin_amdgcn_mfma_i32_16x16x64_i8(a0, bv0, av[0][0], 0, 0, 0);
    av[0][1] = __builtin_amdgcn_mfma_i32_16x16x64_i8(a0, bv1, av[0][1], 0, 0, 0);
    ag[1][0] = __builtin_amdgcn_mfma_i32_16x16x64_i8(a1, bg0, ag[1][0], 0, 0, 0);
    ag[1][1] = __builtin_amdgcn_mfma_i32_16x16x64_i8(a1, bg1, ag[1][1], 0, 0, 0);
    av[1][0] = __builtin_amdgcn_mfma_i32_16x16x64_i8(a1, bv0, av[1][0], 0, 0, 0);
    av[1][1] = __builtin_amdgcn_mfma_i32_16x16x64_i8(a1, bv1, av[1][1], 0, 0, 0);
    ag[2][0] = __builtin_amdgcn_mfma_i32_16x16x64_i8(a2, bg0, ag[2][0], 0, 0, 0);
    ag[2][1] = __builtin_amdgcn_mfma_i32_16x16x64_i8(a2, bg1, ag[2][1], 0, 0, 0);
    av[2][0] = __builtin_amdgcn_mfma_i32_16x16x64_i8(a2, bv0, av[2][0], 0, 0, 0);
    av[2][1] = __builtin_amdgcn_mfma_i32_16x16x64_i8(a2, bv1, av[2][1], 0, 0, 0);
    ag[3][0] = __builtin_amdgcn_mfma_i32_16x16x64_i8(a3, bg0, ag[3][0], 0, 0, 0);
    ag[3][1] = __builtin_amdgcn_mfma_i32_16x16x64_i8(a3, bg1, ag[3][1], 0, 0, 0);
    av[3][0] = __builtin_amdgcn_mfma_i32_16x16x64_i8(a3, bv0, av[3][0], 0, 0, 0);
    av[3][1] = __builtin_amdgcn_mfma_i32_16x16x64_i8(a3, bv1, av[3][1], 0, 0, 0);
    __builtin_amdgcn_s_setprio(0);

    // ---- phase B: stage 2 slabs, publish buf[it+1], read next frags,
    //      16 MFMA on a4..a7 ----
    if (stg) { glds16(src[2] + ko, &Ls[stgo + dst[2]]);
               glds16(src[3] + ko, &Ls[stgo + dst[3]]); }
    if (it <= NT - 3)      asm volatile("s_waitcnt vmcnt(4)" ::: "memory");
    else if (it == NT - 2) asm volatile("s_waitcnt vmcnt(0)" ::: "memory");
    int4v na0, na1, na2, na3, na4, na5, na6, na7, nbg0, nbg1, nbv0, nbv1;
    if (it + 1 < NT) {
      __builtin_amdgcn_s_barrier();   // buf[it+1] published block-wide
      SB0();
      na0 = RD1(nxto + abase);        na1 = RD1(nxto + abase + 1024);
      na2 = RD1(nxto + abase + 2048); na3 = RD1(nxto + abase + 3072);
      na4 = RD1(nxto + abase + 4096); na5 = RD1(nxto + abase + 5120);
      na6 = RD1(nxto + abase + 6144); na7 = RD1(nxto + abase + 7168);
      nbg0 = RD1(nxto + gbase); nbg1 = RD1(nxto + gbase + 1024);
      nbv0 = RD1(nxto + vbase); nbv1 = RD1(nxto + vbase + 1024);
    }
    __builtin_amdgcn_s_setprio(1);
    ag[4][0] = __builtin_amdgcn_mfma_i32_16x16x64_i8(a4, bg0, ag[4][0], 0, 0, 0);
    ag[4][1] = __builtin_amdgcn_mfma_i32_16x16x64_i8(a4, bg1, ag[4][1], 0, 0, 0);
    av[4][0] = __builtin_amdgcn_mfma_i32_16x16x64_i8(a4, bv0, av[4][0], 0, 0, 0);
    av[4][1] = __builtin_amdgcn_mfma_i32_16x16x64_i8(a4, bv1, av[4][1], 0, 0, 0);
    ag[5][0] = __builtin_amdgcn_mfma_i32_16x16x64_i8(a5, bg0, ag[5][0], 0, 0, 0);
    ag[5][1] = __builtin_amdgcn_mfma_i32_16x16x64_i8(a5, bg1, ag[5][1], 0, 0, 0);
    av[5][0] = __builtin_amdgcn_mfma_i32_16x16x64_i8(a5, bv0, av[5][0], 0, 0, 0);
    av[5][1] = __builtin_amdgcn_mfma_i32_16x16x64_i8(a5, bv1, av[5][1], 0, 0, 0);
    ag[6][0] = __builtin_amdgcn_mfma_i32_16x16x64_i8(a6, bg0, ag[6][0], 0, 0, 0);
    ag[6][1] = __builtin_amdgcn_mfma_i32_16x16x64_i8(a6, bg1, ag[6][1], 0, 0, 0);
    av[6][0] = __builtin_amdgcn_mfma_i32_16x16x64_i8(a6, bv0, av[6][0], 0, 0, 0);
    av[6][1] = __builtin_amdgcn_mfma_i32_16x16x64_i8(a6, bv1, av[6][1], 0, 0, 0);
    ag[7][0] = __builtin_amdgcn_mfma_i32_16x16x64_i8(a7, bg0, ag[7][0], 0, 0, 0);
    ag[7][1] = __builtin_amdgcn_mfma_i32_16x16x64_i8(a7, bg1, ag[7][1], 0, 0, 0);
    av[7][0] = __builtin_amdgcn_mfma_i32_16x16x64_i8(a7, bv0, av[7][0], 0, 0, 0);
    av[7][1] = __builtin_amdgcn_mfma_i32_16x16x64_i8(a7, bv1, av[7][1], 0, 0, 0);
    __builtin_amdgcn_s_setprio(0);

    if (it + 1 < NT) {  // rotate fragment registers
      a0 = na0; a1 = na1; a2 = na2; a3 = na3;
      a4 = na4; a5 = na5; a6 = na6; a7 = na7;
      bg0 = nbg0; bg1 = nbg1; bv0 = nbv0; bv1 = nbv1;
    }
    curo = nxto;
  }

  float cg = *cgp;
#pragma unroll
  for (int i = 0; i < 8; ++i)
#pragma unroll
    for (int rr = 0; rr < 4; ++rr) {
      int m = 128 * wr + i * 16 + (l >> 4) * 4 + rr;
      float fs = f1[t0 + m] * cg;
#pragma unroll
      for (int j = 0; j < 2; ++j) {
        int n = 32 * wc + j * 16 + (l & 15);
        float g = (float)ag[i][j][rr] * fs, vv = (float)av[i][j][rr] * fs;
        float z = g / (1.0f + __expf(-g)) * vv;  // silu(g)*v
        Z[(size_t)(t0 + m) * I + n0 + n] = (_Float16)z;
      }
    }
}

// ---------------- GEMM2: out = (Zq @ WdT) * f2 * cd  (f32 output) ----------
// block: 256 tokens x 256 out-cols; 8 waves 2Mx4N, wave = 128x64.
// Same register-pipelined 1-barrier/tile loop as gemm1.
__global__ __launch_bounds__(512, 2) void gemm2_kernel(
    const signed char* __restrict__ A,  // zq [8192,8192] i8
    const signed char* __restrict__ B,  // wdq [2048,8192] i8 ternary
    const float* __restrict__ f2, const float* __restrict__ cdp,
    float* __restrict__ out) {          // [8192,2048] f32
  constexpr int K = 8192, N = 2048, NT = K / 64;
  constexpr int ASZ = 16384, BUF = 32768;
  __shared__ __align__(16) signed char Ls[3 * BUF];
  const int t0 = blockIdx.y * 256, n0 = blockIdx.x * 256;
  const int tid = threadIdx.x, w = tid >> 6, l = tid & 63;
  const int wr = w >> 2, wc = w & 3;
  const int lrow = l & 15, lchunk = (l >> 4) * 16;

  int4v acc[8][4];
#pragma unroll
  for (int i = 0; i < 8; ++i)
#pragma unroll
    for (int j = 0; j < 4; ++j) acc[i][j] = {0,0,0,0};

  // staging: 32 slabs/K-tile; wave w owns A slabs {w, w+8}, B slabs {w, w+8}
  const signed char* src[4];
  int dst[4];
  src[0] = A + (size_t)(t0 + w * 16 + lrow) * K + lchunk;       dst[0] = w * 1024;
  src[1] = A + (size_t)(t0 + (w + 8) * 16 + lrow) * K + lchunk; dst[1] = (w + 8) * 1024;
  src[2] = B + (size_t)(n0 + w * 16 + lrow) * K + lchunk;       dst[2] = ASZ + w * 1024;
  src[3] = B + (size_t)(n0 + (w + 8) * 16 + lrow) * K + lchunk; dst[3] = ASZ + (w + 8) * 1024;

  // prologue: stage tiles 0 and 1
#pragma unroll
  for (int p = 0; p < 2; ++p)
#pragma unroll
    for (int r = 0; r < 4; ++r) glds16(src[r] + p * 64, &Ls[p * BUF + dst[r]]);
  asm volatile("s_waitcnt vmcnt(4)" ::: "memory");
  __builtin_amdgcn_s_barrier();
  SB0();

  const int abase = (8 * wr) * 1024 + l * 16;        // af[i] = +i*1024
  const int bbase = ASZ + (4 * wc) * 1024 + l * 16;  // bf[j] = +j*1024

  int4v a0 = RD1(abase), a1 = RD1(abase + 1024), a2 = RD1(abase + 2048),
        a3 = RD1(abase + 3072), a4 = RD1(abase + 4096), a5 = RD1(abase + 5120),
        a6 = RD1(abase + 6144), a7 = RD1(abase + 7168);
  int4v b0 = RD1(bbase), b1 = RD1(bbase + 1024),
        b2 = RD1(bbase + 2048), b3 = RD1(bbase + 3072);

  int curo = 0;
  for (int it = 0; it < NT; ++it) {
    int nxto = curo + BUF; if (nxto == 3 * BUF) nxto = 0;
    int stgo = nxto + BUF; if (stgo == 3 * BUF) stgo = 0;
    const bool stg = (it <= NT - 3);
    const int ko = (it + 2) * 64;

    // ---- phase A ----
    if (stg) { glds16(src[0] + ko, &Ls[stgo + dst[0]]);
               glds16(src[1] + ko, &Ls[stgo + dst[1]]); }
    __builtin_amdgcn_s_setprio(1);
    acc[0][0] = __builtin_amdgcn_mfma_i32_16x16x64_i8(a0, b0, acc[0][0], 0, 0, 0);
    acc[0][1] = __builtin_amdgcn_mfma_i32_16x16x64_i8(a0, b1, acc[0][1], 0, 0, 0);
    acc[0][2] = __builtin_amdgcn_mfma_i32_16x16x64_i8(a0, b2, acc[0][2], 0, 0, 0);
    acc[0][3] = __builtin_amdgcn_mfma_i32_16x16x64_i8(a0, b3, acc[0][3], 0, 0, 0);
    acc[1][0] = __builtin_amdgcn_mfma_i32_16x16x64_i8(a1, b0, acc[1][0], 0, 0, 0);
    acc[1][1] = __builtin_amdgcn_mfma_i32_16x16x64_i8(a1, b1, acc[1][1], 0, 0, 0);
    acc[1][2] = __builtin_amdgcn_mfma_i32_16x16x64_i8(a1, b2, acc[1][2], 0, 0, 0);
    acc[1][3] = __builtin_amdgcn_mfma_i32_16x16x64_i8(a1, b3, acc[1][3], 0, 0, 0);
    acc[2][0] = __builtin_amdgcn_mfma_i32_16x16x64_i8(a2, b0, acc[2][0], 0, 0, 0);
    acc[2][1] = __builtin_amdgcn_mfma_i32_16x16x64_i8(a2, b1, acc[2][1], 0, 0, 0);
    acc[2][2] = __builtin_amdgcn_mfma_i32_16x16x64_i8(a2, b2, acc[2][2], 0, 0, 0);
    acc[2][3] = __builtin_amdgcn_mfma_i32_16x16x64_i8(a2, b3, acc[2][3], 0, 0, 0);
    acc[3][0] = __builtin_amdgcn_mfma_i32_16x16x64_i8(a3, b0, acc[3][0], 0, 0, 0);
    acc[3][1] = __builtin_amdgcn_mfma_i32_16x16x64_i8(a3, b1, acc[3][1], 0, 0, 0);
    acc[3][2] = __builtin_amdgcn_mfma_i32_16x16x64_i8(a3, b2, acc[3][2], 0, 0, 0);
    acc[3][3] = __builtin_amdgcn_mfma_i32_16x16x64_i8(a3, b3, acc[3][3], 0, 0, 0);
    __builtin_amdgcn_s_setprio(0);

    // ---- phase B ----
    if (stg) { glds16(src[2] + ko, &Ls[stgo + dst[2]]);
               glds16(src[3] + ko, &Ls[stgo + dst[3]]); }
    if (it <= NT - 3)      asm volatile("s_waitcnt vmcnt(4)" ::: "memory");
    else if (it == NT - 2) asm volatile("s_waitcnt vmcnt(0)" ::: "memory");
    int4v na0, na1, na2, na3, na4, na5, na6, na7, nb0, nb1, nb2, nb3;
    if (it + 1 < NT) {
      __builtin_amdgcn_s_barrier();
      SB0();
      na0 = RD1(nxto + abase);        na1 = RD1(nxto + abase + 1024);
      na2 = RD1(nxto + abase + 2048); na3 = RD1(nxto + abase + 3072);
      na4 = RD1(nxto + abase + 4096); na5 = RD1(nxto + abase + 5120);
      na6 = RD1(nxto + abase + 6144); na7 = RD1(nxto + abase + 7168);
      nb0 = RD1(nxto + bbase);        nb1 = RD1(nxto + bbase + 1024);
      nb2 = RD1(nxto + bbase + 2048); nb3 = RD1(nxto + bbase + 3072);
    }
    __builtin_amdgcn_s_setprio(1);
    acc[4][0] = __builtin_amdgcn_mfma_i32_16x16x64_i8(a4, b0, acc[4][0], 0, 0, 0);
    acc[4][1] = __builtin_amdgcn_mfma_i32_16x16x64_i8(a4, b1, acc[4][1], 0, 0, 0);
    acc[4][2] = __builtin_amdgcn_mfma_i32_16x16x64_i8(a4, b2, acc[4][2], 0, 0, 0);
    acc[4][3] = __builtin_amdgcn_mfma_i32_16x16x64_i8(a4, b3, acc[4][3], 0, 0, 0);
    acc[5][0] = __builtin_amdgcn_mfma_i32_16x16x64_i8(a5, b0, acc[5][0], 0, 0, 0);
    acc[5][1] = __builtin_amdgcn_mfma_i32_16x16x64_i8(a5, b1, acc[5][1], 0, 0, 0);
    acc[5][2] = __builtin_amdgcn_mfma_i32_16x16x64_i8(a5, b2, acc[5][2], 0, 0, 0);
    acc[5][3] = __builtin_amdgcn_mfma_i32_16x16x64_i8(a5, b3, acc[5][3], 0, 0, 0);
    acc[6][0] = __builtin_amdgcn_mfma_i32_16x16x64_i8(a6, b0, acc[6][0], 0, 0, 0);
    acc[6][1] = __builtin_amdgcn_mfma_i32_16x16x64_i8(a6, b1, acc[6][1], 0, 0, 0);
    acc[6][2] = __builtin_amdgcn_mfma_i32_16x16x64_i8(a6, b2, acc[6][2], 0, 0, 0);
    acc[6][3] = __builtin_amdgcn_mfma_i32_16x16x64_i8(a6, b3, acc[6][3], 0, 0, 0);
    acc[7][0] = __builtin_amdgcn_mfma_i32_16x16x64_i8(a7, b0, acc[7][0], 0, 0, 0);
    acc[7][1] = __builtin_amdgcn_mfma_i32_16x16x64_i8(a7, b1, acc[7][1], 0, 0, 0);
    acc[7][2] = __builtin_amdgcn_mfma_i32_16x16x64_i8(a7, b2, acc[7][2], 0, 0, 0);
    acc[7][3] = __builtin_amdgcn_mfma_i32_16x16x64_i8(a7, b3, acc[7][3], 0, 0, 0);
    __builtin_amdgcn_s_setprio(0);

    if (it + 1 < NT) {
      a0 = na0; a1 = na1; a2 = na2; a3 = na3;
      a4 = na4; a5 = na5; a6 = na6; a7 = na7;
      b0 = nb0; b1 = nb1; b2 = nb2; b3 = nb3;
    }
    curo = nxto;
  }

  float cd = *cdp;
#pragma unroll
  for (int i = 0; i < 8; ++i)
#pragma unroll
    for (int rr = 0; rr < 4; ++rr) {
      int m = 128 * wr + i * 16 + (l >> 4) * 4 + rr;
      float fs = f2[t0 + m] * cd;
#pragma unroll
      for (int j = 0; j < 4; ++j) {
        int n = 64 * wc + j * 16 + (l & 15);
        out[(size_t)(t0 + m) * N + n0 + n] = (float)acc[i][j][rr] * fs;
      }
    }
}

extern "C" void kernel_launch(void* const* d_in, const int* in_sizes, int n_in,
                              void* d_out, int out_size, void* d_ws, size_t ws_size,
                              hipStream_t stream) {
  const float* x  = (const float*)d_in[0];  // [8192,2048] f32
  const float* wg = (const float*)d_in[1];  // [16384,2048] f32
  const float* wd = (const float*)d_in[2];  // [2048,8192] f32
  float* out = (float*)d_out;               // [8192,2048] f32

  // workspace layout (~268.5 MB)
  char* ws = (char*)d_ws;
  signed char* wgq = (signed char*)(ws);                 //  33,554,432 B
  signed char* wdq = (signed char*)(ws + 33554432);      //  16,777,216 B
  signed char* xq  = (signed char*)(ws + 50331648);      //  16,777,216 B
  signed char* zq  = (signed char*)(ws + 67108864);      //  67,108,864 B
  _Float16*    z   = (_Float16*)  (ws + 134217728);      // 134,217,728 B
  float* f1     = (float*)(ws + 268435456);              //      32,768 B
  float* f2     = (float*)(ws + 268468224);              //      32,768 B
  float* pf     = (float*)(ws + 268500992);              //       8,192 B
  float* scales = (float*)(ws + 268509184);              //          16 B

  // 1) global mean(|w|) for both weight matrices (deterministic, no atomics)
  reduce_abs_kernel<<<1024, 256, 0, stream>>>((const float4*)wg, pf, 8388608);
  reduce_abs_kernel<<<1024, 256, 0, stream>>>((const float4*)wd, pf + 1024, 4194304);
  finalize_kernel<<<1, 256, 0, stream>>>(pf, scales);

  // 2) ternarize weights, int8-quantize activations
  quant_weight_kernel<<<2048, 256, 0, stream>>>((const float4*)wg, (char8*)wgq, scales + 2, 4194304);
  quant_weight_kernel<<<1024, 256, 0, stream>>>((const float4*)wd, (char8*)wdq, scales + 3, 2097152);
  act_quant_f32_kernel<<<8192, 256, 0, stream>>>(x, xq, f1);

  // 3) GEMM1 (i8) fused with dequant + silu*v -> z (fp16)
  gemm1_kernel<<<dim3(64, 32), 512, 0, stream>>>(xq, wgq, f1, scales, z);

  // 4) quantize z -> zq (i8) + f2
  act_quant_h_kernel<<<8192, 256, 0, stream>>>(z, zq, f2);

  // 5) GEMM2 (i8) fused with dequant -> out (f32)
  gemm2_kernel<<<dim3(8, 32), 512, 0, stream>>>(zq, wdq, f2, scales + 1, out);
}